// Round 13
// baseline (236.631 us; speedup 1.0000x reference)
//
#include <hip/hip_runtime.h>
#include <hip/hip_fp16.h>

typedef unsigned short u16;
typedef __bf16 bf16x8 __attribute__((ext_vector_type(8)));
typedef float f32x4 __attribute__((ext_vector_type(4)));
typedef float f32x16 __attribute__((ext_vector_type(16)));

#define MFMA16(a, b, c) __builtin_amdgcn_mfma_f32_16x16x32_bf16(a, b, c, 0, 0, 0)
#define MFMA32(a, b, c) __builtin_amdgcn_mfma_f32_32x32x16_bf16(a, b, c, 0, 0, 0)

constexpr float LOG2E = 1.44269504088896340736f;

__device__ __forceinline__ u16 f2bf(float x) {
  unsigned u = __float_as_uint(x);
  u += 0x7fffu + ((u >> 16) & 1u);  // RNE
  return (u16)(u >> 16);
}
// round-half-up; valid for positive finite; 2 instrs
__device__ __forceinline__ u16 f2bf_fast(float x) {
  return (u16)((__float_as_uint(x) + 0x8000u) >> 16);
}

struct FalseT { static constexpr bool value = false; };
struct TrueT  { static constexpr bool value = true;  };

// ---------------- transpose+convert weights: Wt[n][k] = W[k][n], bf16 (z selects W) ----
__global__ void transpose_w_kernel(const float* __restrict__ w0, const float* __restrict__ w1,
                                   const float* __restrict__ w2, const float* __restrict__ w3,
                                   u16* __restrict__ wt) {
  __shared__ float tile[32][33];
  const float* W = blockIdx.z == 0 ? w0 : blockIdx.z == 1 ? w1 : blockIdx.z == 2 ? w2 : w3;
  u16* T = wt + (size_t)blockIdx.z * 512 * 512;
  int tx = threadIdx.x, ty = threadIdx.y;
  int x = blockIdx.x * 32 + tx;
  int y0 = blockIdx.y * 32;
#pragma unroll
  for (int i = 0; i < 32; i += 8) tile[ty + i][tx] = W[(y0 + ty + i) * 512 + x];
  __syncthreads();
  int xo = blockIdx.y * 32 + tx;
  int r0 = blockIdx.x * 32;
#pragma unroll
  for (int i = 0; i < 32; i += 8) T[(r0 + ty + i) * 512 + xo] = f2bf(tile[tx][ty + i]);
}

// ---------------- fused q/k/vT projection GEMM, tile 128(M)x64(N), K=512 --------------
// blocks [0,512): q/k-proj (z=id>>8). q (z=0): row-major [bh][q][dh], scaled 0.125*LOG2E.
//   k (z=1): MFMA-A-frag-major layout [bh][kt][t][st][lane][8] for direct attn frag loads.
// blocks [512,768): vT-proj -> V-frag layout [bh][kt][h2][st][lane][8].
__global__ __launch_bounds__(256) void qkv_gemm(
    const float* __restrict__ qs, const float* __restrict__ ks, const float* __restrict__ vs,
    const u16* __restrict__ Wt, const float* __restrict__ bq, const float* __restrict__ bk,
    const float* __restrict__ bv, u16* __restrict__ qg, u16* __restrict__ kg,
    u16* __restrict__ vTg) {
  __shared__ u16 As[128 * 72];
  __shared__ u16 Bs[64 * 72];
  const int tid = threadIdx.x;
  const int wave = tid >> 6, lane = tid & 63;
  const int l15 = lane & 15, quad = lane >> 4;
  const int id = blockIdx.x;
  const bool qk = id < 512;
  int z = 0, m0, n0;
  const float* Af = nullptr;
  const u16* Ab = nullptr;
  const u16* Bb = nullptr;
  const float* Bf = nullptr;
  if (qk) {
    z = id >> 8;
    int t = id & 255;
    m0 = (t >> 3) * 128;
    n0 = (t & 7) * 64;
    Af = z ? ks : qs;
    Bb = Wt + z * 262144;
  } else {
    int t = id - 512;
    m0 = (t >> 6) * 128;
    n0 = (t & 63) * 64;
    Ab = Wt + 2 * 262144;
    Bf = vs;
  }
  f32x4 acc[2][4];
#pragma unroll
  for (int i = 0; i < 2; i++)
#pragma unroll
    for (int j = 0; j < 4; j++) {
      f32x4 zr = {0.f, 0.f, 0.f, 0.f};
      acc[i][j] = zr;
    }
  const int srA = tid >> 1, scA = (tid & 1) * 32;
  const int srB = tid >> 2, scB = (tid & 3) * 16;
  for (int k0 = 0; k0 < 512; k0 += 64) {
    if (qk) {
      const float* ga = Af + (m0 + srA) * 512 + k0 + scA;
      u16* la = As + srA * 72 + scA;
#pragma unroll
      for (int c = 0; c < 4; ++c) {
        float4 f0 = *(const float4*)(ga + c * 8);
        float4 f1 = *(const float4*)(ga + c * 8 + 4);
        uint4 u;
        u.x = f2bf(f0.x) | ((unsigned)f2bf(f0.y) << 16);
        u.y = f2bf(f0.z) | ((unsigned)f2bf(f0.w) << 16);
        u.z = f2bf(f1.x) | ((unsigned)f2bf(f1.y) << 16);
        u.w = f2bf(f1.z) | ((unsigned)f2bf(f1.w) << 16);
        *(uint4*)(la + c * 8) = u;
      }
      const u16* gb = Bb + (n0 + srB) * 512 + k0 + scB;
      u16* lb = Bs + srB * 72 + scB;
      *(uint4*)(lb) = *(const uint4*)(gb);
      *(uint4*)(lb + 8) = *(const uint4*)(gb + 8);
    } else {
      const u16* ga = Ab + (m0 + srA) * 512 + k0 + scA;
      u16* la = As + srA * 72 + scA;
#pragma unroll
      for (int c = 0; c < 4; ++c) *(uint4*)(la + c * 8) = *(const uint4*)(ga + c * 8);
      const float* gb = Bf + (n0 + srB) * 512 + k0 + scB;
      u16* lb = Bs + srB * 72 + scB;
#pragma unroll
      for (int c = 0; c < 2; ++c) {
        float4 f0 = *(const float4*)(gb + c * 8);
        float4 f1 = *(const float4*)(gb + c * 8 + 4);
        uint4 u;
        u.x = f2bf(f0.x) | ((unsigned)f2bf(f0.y) << 16);
        u.y = f2bf(f0.z) | ((unsigned)f2bf(f0.w) << 16);
        u.z = f2bf(f1.x) | ((unsigned)f2bf(f1.y) << 16);
        u.w = f2bf(f1.z) | ((unsigned)f2bf(f1.w) << 16);
        *(uint4*)(lb + c * 8) = u;
      }
    }
    __syncthreads();
#pragma unroll
    for (int st = 0; st < 2; ++st) {
      bf16x8 af[2], bfr[4];
#pragma unroll
      for (int mt = 0; mt < 2; ++mt)
        af[mt] = *(const bf16x8*)(As + (wave * 32 + mt * 16 + l15) * 72 + st * 32 + quad * 8);
#pragma unroll
      for (int nt = 0; nt < 4; ++nt)
        bfr[nt] = *(const bf16x8*)(Bs + (nt * 16 + l15) * 72 + st * 32 + quad * 8);
#pragma unroll
      for (int mt = 0; mt < 2; ++mt)
#pragma unroll
        for (int nt = 0; nt < 4; ++nt) acc[mt][nt] = MFMA16(af[mt], bfr[nt], acc[mt][nt]);
    }
    __syncthreads();
  }
  if (qk) {
    const float* bias = z ? bk : bq;
    const float scale = z ? 1.0f : 0.125f * LOG2E;
#pragma unroll
    for (int mt = 0; mt < 2; ++mt)
#pragma unroll
      for (int nt = 0; nt < 4; ++nt)
#pragma unroll
        for (int r = 0; r < 4; ++r) {
          int row = m0 + wave * 32 + mt * 16 + quad * 4 + r;
          int col = n0 + nt * 16 + l15;
          float v = (acc[mt][nt][r] + bias[col]) * scale;
          int b = row >> 11, key = row & 2047, hh = col >> 6, dh = col & 63;
          int bhh = b * 8 + hh;
          if (z == 0) {
            qg[((bhh * 2048) + key) * 64 + dh] = f2bf(v);
          } else {
            int kt = key >> 6, tt = (key >> 5) & 1, lk = key & 31;
            int st = dh >> 4, hif = (dh >> 3) & 1, j = dh & 7;
            kg[(size_t)(bhh * 32 + kt) * 4096 + tt * 2048 + st * 512 + (hif * 32 + lk) * 8 +
               j] = f2bf(v);
          }
        }
  } else {
#pragma unroll
    for (int mt = 0; mt < 2; ++mt)
#pragma unroll
      for (int nt = 0; nt < 4; ++nt)
#pragma unroll
        for (int r = 0; r < 4; ++r) {
          int row = m0 + wave * 32 + mt * 16 + quad * 4 + r;  // dm = h*64+dh
          int col = n0 + nt * 16 + l15;                        // b*2048+key
          int hh = row >> 6, dh = row & 63, b = col >> 11, key = col & 2047;
          int bhh = b * 8 + hh;
          int kt = key >> 6, kk = key & 63, st = kk >> 4, hif = (kk >> 3) & 1, j = kk & 7;
          int h2 = dh >> 5, lk = dh & 31;
          vTg[(size_t)(bhh * 32 + kt) * 4096 + h2 * 2048 + st * 512 + (hif * 32 + lk) * 8 + j] =
              f2bf(acc[mt][nt][r] + bv[row]);
        }
  }
}

// ---------------- flash attention, 32x32 MFMA, frag-direct K/V, 4-way K-split ---------
// grid (Q/128, B*H, 4), block 256 = 4 waves x 32 q. Wave tile: 32 q x 64 keys.
// P round-trips through wave-private LDS (lgkm drain, no barrier). Nearest-bin 2048-entry
// f32 bias table. K-frags DOUBLE-BUFFERED across tiles: body(kt) first issues kt+1's
// 8 global loads into the alternate register buffer (ping-pong call sites, no copies),
// hiding the ~300-500cyc VMEM latency behind kt's MFMA+softmax.
__global__ __launch_bounds__(256, 3) void attn_kernel(
    const u16* __restrict__ qg, const u16* __restrict__ kfrag, const u16* __restrict__ vfrag,
    const float* __restrict__ qlocs, const float* __restrict__ klocs,
    const float* __restrict__ aP, const float* __restrict__ bP, const float* __restrict__ cP,
    const int* __restrict__ vlen, u16* __restrict__ Opart, float* __restrict__ lpart) {
  constexpr int TBLN = 2048;
  constexpr float DMAX = 14.16f;  // > 10*sqrt(2) = 14.1422
  constexpr float TSCALE = (float)TBLN / DMAX;
  __shared__ u16 Ps[4][32 * 68];           // per-wave P, [q][key]  (17408 B)
  __shared__ alignas(16) float2 klb[576];  // this z-chunk's key locs (<=9 tiles), scaled
  __shared__ float tbl[TBLN];              // g(bin center)*log2e   (8192 B)
  const int tid = threadIdx.x;
  const int wave = tid >> 6, lane = tid & 63;
  const int l31 = lane & 31, hi = lane >> 5;
  const int bh = blockIdx.y, b = bh >> 3, h = bh & 7;
  const int z = blockIdx.z;
  const int vl = vlen[b];
  const int ntiles = (vl + 63) >> 6;  // in [16,32]
  const int nfull = vl >> 6;
  const int tb = ntiles >> 2, rem = ntiles & 3;  // tb >= 4: every chunk has >=3 full tiles
  const int kt0 = z * tb + (z < rem ? z : rem);
  const int ktend = kt0 + tb + (z < rem ? 1 : 0);

  // per-head bias table at bin centers, log2 domain
  for (int i = tid; i < TBLN; i += 256) {
    float d = (i + 0.5f) * (DMAX / TBLN);
    float g = 0.f;
#pragma unroll
    for (int f = 0; f < 5; ++f) {
      float t = d - cP[h * 5 + f];
      g += aP[h * 5 + f] * __expf(-fabsf(bP[h * 5 + f]) * t * t);
    }
    tbl[i] = g * LOG2E;
  }
  // stage this chunk's key locations once (covers all tiles incl. the partial one)
  const int nk = (ktend - kt0) * 64;
  for (int i = tid; i < nk; i += 256) {
    float2 kl = *(const float2*)(klocs + (b * 2048 + kt0 * 64 + i) * 2);
    klb[i] = make_float2(kl.x * TSCALE, kl.y * TSCALE);
  }
  __syncthreads();  // tbl + klb visible; the ONLY block barrier

  const int qrow = blockIdx.x * 128 + wave * 32 + l31;
  bf16x8 aq[4];  // Q B-operand: B[k=dh][n=q], k = st*16 + hi*8 + j
  {
    const u16* qr = qg + (bh * 2048 + qrow) * 64 + hi * 8;
#pragma unroll
    for (int st = 0; st < 4; ++st) aq[st] = *(const bf16x8*)(qr + st * 16);
  }
  float qpx, qpy;
  {
    float2 p = *(const float2*)(qlocs + (b * 2048 + qrow) * 2);
    qpx = p.x * TSCALE;
    qpy = p.y * TSCALE;
  }
  float l_ = 0.f;
  f32x16 oacc[2];
#pragma unroll
  for (int i = 0; i < 2; ++i)
#pragma unroll
    for (int j = 0; j < 16; ++j) oacc[i][j] = 0.f;
  u16* pw = Ps[wave];

  auto load_kf = [&](int kt, bf16x8 (&kf)[2][4]) {
    const u16* fb = kfrag + (size_t)(bh * 32 + kt) * 4096 + lane * 8;
#pragma unroll
    for (int t = 0; t < 2; ++t)
#pragma unroll
      for (int st = 0; st < 4; ++st)
        kf[t][st] = *(const bf16x8*)(fb + t * 2048 + st * 512);  // coalesced 1KB global
  };

  auto body = [&](int kt, auto mc, bf16x8 (&kfC)[2][4], bf16x8 (&kfN)[2][4], int nxt) {
    constexpr bool MASKED = decltype(mc)::value;
    if (nxt >= 0) load_kf(nxt, kfN);  // prefetch next tile (fire-and-forget)
    const int k0 = kt * 64;
    const int rt64 = (kt - kt0) * 64;
    const u16* vb = vfrag + (size_t)(bh * 32 + kt) * 4096 + lane * 8;
#pragma unroll
    for (int t = 0; t < 2; ++t) {
      // S^T = K*Q^T: D[key = t*32 + (reg&3)+8*(reg>>2)+4*hi][q = l31]
      f32x16 s;
#pragma unroll
      for (int j = 0; j < 16; ++j) s[j] = 0.f;
#pragma unroll
      for (int st = 0; st < 4; ++st) s = MFMA32(kfC[t][st], aq[st], s);
      // bias (nearest-bin lookup) + exp2 + P write, per 4-key group
#pragma unroll
      for (int g = 0; g < 4; ++g) {
        const int kl0 = t * 32 + hi * 4 + g * 8;
        float4 ka = *(const float4*)(&klb[rt64 + kl0]);      // keys kl0, kl0+1
        float4 kb = *(const float4*)(&klb[rt64 + kl0 + 2]);  // keys kl0+2, kl0+3
        float kx[4] = {ka.x, ka.z, kb.x, kb.z};
        float ky[4] = {ka.y, ka.w, kb.y, kb.w};
        float p[4];
#pragma unroll
        for (int j = 0; j < 4; ++j) {
          float dx = qpx - kx[j], dy = qpy - ky[j];
          float t_ = __builtin_amdgcn_sqrtf(fmaf(dx, dx, dy * dy));  // = d * TSCALE
          int ti = (int)t_;  // <= 2045 by construction
          float v = s[g * 4 + j] + tbl[ti];
          if (MASKED) v = (k0 + kl0 + j < vl) ? v : -1e30f;
          p[j] = __builtin_amdgcn_exp2f(v);
          l_ += p[j];
        }
        uint2 w;
        w.x = f2bf_fast(p[0]) | ((unsigned)f2bf_fast(p[1]) << 16);
        w.y = f2bf_fast(p[2]) | ((unsigned)f2bf_fast(p[3]) << 16);
        *(uint2*)(pw + l31 * 68 + kl0) = w;
      }
    }
    // V-frag loads issued before the LDS drain: VMEM latency overlaps drain + pf reads
    bf16x8 vf[2][4];
#pragma unroll
    for (int h2 = 0; h2 < 2; ++h2)
#pragma unroll
      for (int st = 0; st < 4; ++st)
        vf[h2][st] = *(const bf16x8*)(vb + h2 * 2048 + st * 512);  // coalesced 1KB global
    // P tile wave-private: drain LDS writes, no barrier
    __asm__ volatile("s_waitcnt lgkmcnt(0)" ::: "memory");
    // O^T += V^T * P: D[dh][q = l31]
#pragma unroll
    for (int st = 0; st < 4; ++st) {
      bf16x8 pf = *(const bf16x8*)(pw + l31 * 68 + st * 16 + hi * 8);
#pragma unroll
      for (int h2 = 0; h2 < 2; ++h2) oacc[h2] = MFMA32(vf[h2][st], pf, oacc[h2]);
    }
  };

  const int fullend = ktend < nfull ? ktend : nfull;  // >= kt0+3 always
  bf16x8 kA[2][4], kB[2][4];
  load_kf(kt0, kA);
  bool useA = true;
  for (int kt = kt0; kt < fullend; ++kt) {
    const int nxt = (kt + 1 < fullend) ? (kt + 1) : ((ktend > nfull) ? nfull : -1);
    if (useA) body(kt, FalseT{}, kA, kB, nxt);
    else      body(kt, FalseT{}, kB, kA, nxt);
    useA = !useA;
  }
  if (ktend > nfull) {
    if (useA) body(nfull, TrueT{}, kA, kB, -1);
    else      body(nfull, TrueT{}, kB, kA, -1);
  }

  l_ += __shfl_xor(l_, 32);
  if (hi == 0) lpart[z * 32768 + bh * 2048 + qrow] = l_;
  u16* ob = Opart + ((size_t)(z * 16 + bh) * 2048 + qrow) * 64;
#pragma unroll
  for (int h2 = 0; h2 < 2; ++h2)
#pragma unroll
    for (int g = 0; g < 4; ++g) {
      const int dh0 = h2 * 32 + hi * 4 + g * 8;
      uint2 w;
      w.x = f2bf(oacc[h2][g * 4 + 0]) | ((unsigned)f2bf(oacc[h2][g * 4 + 1]) << 16);
      w.y = f2bf(oacc[h2][g * 4 + 2]) | ((unsigned)f2bf(oacc[h2][g * 4 + 3]) << 16);
      *(uint2*)(ob + dh0) = w;
    }
}

// ---------------- O-projection GEMM with fused 4-partial combine ----------------------
// tile 64x64, grid (64,8) = 512 blocks (2/CU, 16 waves/CU). A-stage sums the 4 z-partials
// (contiguous 64-elem rows per z, fully coalesced), normalizes by sum(lpart), packs bf16.
__global__ __launch_bounds__(256) void out_gemm(const u16* __restrict__ Opart,
                                                const float* __restrict__ lpart,
                                                const u16* __restrict__ Wt,
                                                const float* __restrict__ bo,
                                                float* __restrict__ out) {
  __shared__ u16 As[64 * 72];
  __shared__ u16 Bs[64 * 72];
  const u16* WoT = Wt + 3 * 262144;
  const int tid = threadIdx.x;
  const int wave = tid >> 6, lane = tid & 63;
  const int l15 = lane & 15, quad = lane >> 4;
  const int m0 = blockIdx.x * 64, n0 = blockIdx.y * 64;
  f32x4 acc[4];
#pragma unroll
  for (int j = 0; j < 4; j++) {
    f32x4 zr = {0.f, 0.f, 0.f, 0.f};
    acc[j] = zr;
  }
  const int sr = tid >> 2, sc = (tid & 3) * 16;
  const int row = m0 + sr, b = row >> 11, qq = row & 2047;
  for (int k0 = 0; k0 < 512; k0 += 64) {
    const int h = k0 >> 6;
    const int base = (b * 8 + h) * 2048 + qq;  // row into [z][32768] partial space
    float l = lpart[base] + lpart[32768 + base] + lpart[2 * 32768 + base] +
              lpart[3 * 32768 + base];
    const float inv = 1.f / l;
    float vals[16];
#pragma unroll
    for (int e = 0; e < 16; ++e) vals[e] = 0.f;
#pragma unroll
    for (int zz = 0; zz < 4; ++zz) {
      const u16* op = Opart + ((size_t)(zz * 32768) + base) * 64 + sc;
#pragma unroll
      for (int c = 0; c < 2; ++c) {
        bf16x8 o8 = *(const bf16x8*)(op + c * 8);
#pragma unroll
        for (int j = 0; j < 8; ++j) vals[c * 8 + j] += (float)o8[j];
      }
    }
    u16* la = As + sr * 72 + sc;
#pragma unroll
    for (int c = 0; c < 2; ++c) {
      uint4 u;
      u.x = f2bf(vals[c * 8 + 0] * inv) | ((unsigned)f2bf(vals[c * 8 + 1] * inv) << 16);
      u.y = f2bf(vals[c * 8 + 2] * inv) | ((unsigned)f2bf(vals[c * 8 + 3] * inv) << 16);
      u.z = f2bf(vals[c * 8 + 4] * inv) | ((unsigned)f2bf(vals[c * 8 + 5] * inv) << 16);
      u.w = f2bf(vals[c * 8 + 6] * inv) | ((unsigned)f2bf(vals[c * 8 + 7] * inv) << 16);
      *(uint4*)(la + c * 8) = u;
    }
    const u16* gb = WoT + (n0 + sr) * 512 + k0 + sc;
    u16* lb = Bs + sr * 72 + sc;
    *(uint4*)(lb) = *(const uint4*)(gb);
    *(uint4*)(lb + 8) = *(const uint4*)(gb + 8);
    __syncthreads();
#pragma unroll
    for (int st = 0; st < 2; ++st) {
      bf16x8 af = *(const bf16x8*)(As + (wave * 16 + l15) * 72 + st * 32 + quad * 8);
#pragma unroll
      for (int nt = 0; nt < 4; ++nt) {
        bf16x8 bfr = *(const bf16x8*)(Bs + (nt * 16 + l15) * 72 + st * 32 + quad * 8);
        acc[nt] = MFMA16(af, bfr, acc[nt]);
      }
    }
    __syncthreads();
  }
#pragma unroll
  for (int nt = 0; nt < 4; ++nt)
#pragma unroll
    for (int r = 0; r < 4; ++r) {
      int rrow = m0 + wave * 16 + quad * 4 + r;
      int col = n0 + nt * 16 + l15;
      out[rrow * 512 + col] = acc[nt][r] + bo[col];
    }
}

extern "C" void kernel_launch(void* const* d_in, const int* in_sizes, int n_in, void* d_out,
                              int out_size, void* d_ws, size_t ws_size, hipStream_t stream) {
  const float* qs = (const float*)d_in[0];
  const float* ks = (const float*)d_in[1];
  const float* vs = (const float*)d_in[2];
  const float* qlocs = (const float*)d_in[3];
  const float* klocs = (const float*)d_in[4];
  const float* Wq = (const float*)d_in[5];
  const float* bq = (const float*)d_in[6];
  const float* Wk = (const float*)d_in[7];
  const float* bk = (const float*)d_in[8];
  const float* Wv = (const float*)d_in[9];
  const float* bv = (const float*)d_in[10];
  const float* Wo = (const float*)d_in[11];
  const float* bo = (const float*)d_in[12];
  const float* aP = (const float*)d_in[13];
  const float* bP = (const float*)d_in[14];
  const float* cP = (const float*)d_in[15];
  const int* vlen = (const int*)d_in[16];
  float* out = (float*)d_out;

  u16* Wt = (u16*)d_ws;        // 4 x [512,512] bf16 W^T (2 MB)
  u16* qg = Wt + 4 * 262144;   // [B,H,Q,DH] bf16 row-major (4 MB)
  u16* kg = qg + 2097152;      // K-frag layout [bh][kt][t][st][lane][8] (4 MB)
  u16* vTg = kg + 2097152;     // V-frag layout [bh][kt][h2][st][lane][8] (4 MB)
  u16* Opart = vTg + 2097152;  // [4][16][2048][64] bf16 (16 MB)
  float* lpart = (float*)(Opart + (size_t)4 * 2097152);  // [4][32768]

  transpose_w_kernel<<<dim3(16, 16, 4), dim3(32, 8), 0, stream>>>(Wq, Wk, Wv, Wo, Wt);
  qkv_gemm<<<768, 256, 0, stream>>>(qs, ks, vs, Wt, bq, bk, bv, qg, kg, vTg);
  attn_kernel<<<dim3(16, 16, 4), 256, 0, stream>>>(qg, kg, vTg, qlocs, klocs, aP, bP, cP, vlen,
                                                   Opart, lpart);
  out_gemm<<<dim3(64, 8), 256, 0, stream>>>(Opart, lpart, Wt, bo, out);
}

// Round 14
// 181.716 us; speedup vs baseline: 1.3022x; 1.3022x over previous
//
#include <hip/hip_runtime.h>
#include <hip/hip_fp16.h>

typedef unsigned short u16;
typedef __bf16 bf16x8 __attribute__((ext_vector_type(8)));
typedef float f32x4 __attribute__((ext_vector_type(4)));
typedef float f32x16 __attribute__((ext_vector_type(16)));

#define MFMA16(a, b, c) __builtin_amdgcn_mfma_f32_16x16x32_bf16(a, b, c, 0, 0, 0)
#define MFMA32(a, b, c) __builtin_amdgcn_mfma_f32_32x32x16_bf16(a, b, c, 0, 0, 0)

constexpr float LOG2E = 1.44269504088896340736f;

__device__ __forceinline__ u16 f2bf(float x) {
  unsigned u = __float_as_uint(x);
  u += 0x7fffu + ((u >> 16) & 1u);  // RNE
  return (u16)(u >> 16);
}
// round-half-up; valid for positive finite; 2 instrs
__device__ __forceinline__ u16 f2bf_fast(float x) {
  return (u16)((__float_as_uint(x) + 0x8000u) >> 16);
}

struct FalseT { static constexpr bool value = false; };
struct TrueT  { static constexpr bool value = true;  };

// ---------------- transpose+convert weights: Wt[n][k] = W[k][n], bf16 (z selects W) ----
__global__ void transpose_w_kernel(const float* __restrict__ w0, const float* __restrict__ w1,
                                   const float* __restrict__ w2, const float* __restrict__ w3,
                                   u16* __restrict__ wt) {
  __shared__ float tile[32][33];
  const float* W = blockIdx.z == 0 ? w0 : blockIdx.z == 1 ? w1 : blockIdx.z == 2 ? w2 : w3;
  u16* T = wt + (size_t)blockIdx.z * 512 * 512;
  int tx = threadIdx.x, ty = threadIdx.y;
  int x = blockIdx.x * 32 + tx;
  int y0 = blockIdx.y * 32;
#pragma unroll
  for (int i = 0; i < 32; i += 8) tile[ty + i][tx] = W[(y0 + ty + i) * 512 + x];
  __syncthreads();
  int xo = blockIdx.y * 32 + tx;
  int r0 = blockIdx.x * 32;
#pragma unroll
  for (int i = 0; i < 32; i += 8) T[(r0 + ty + i) * 512 + xo] = f2bf(tile[tx][ty + i]);
}

// ---------------- fused q/k/vT projection GEMM, tile 128(M)x64(N), K=512 --------------
// blocks [0,512): q/k-proj (z=id>>8). q (z=0): row-major [bh][q][dh], scaled 0.125*LOG2E.
//   k (z=1): MFMA-A-frag-major layout [bh][kt][t][st][lane][8] for direct attn frag loads.
// blocks [512,768): vT-proj -> V-frag layout [bh][kt][h2][st][lane][8].
__global__ __launch_bounds__(256) void qkv_gemm(
    const float* __restrict__ qs, const float* __restrict__ ks, const float* __restrict__ vs,
    const u16* __restrict__ Wt, const float* __restrict__ bq, const float* __restrict__ bk,
    const float* __restrict__ bv, u16* __restrict__ qg, u16* __restrict__ kg,
    u16* __restrict__ vTg) {
  __shared__ u16 As[128 * 72];
  __shared__ u16 Bs[64 * 72];
  const int tid = threadIdx.x;
  const int wave = tid >> 6, lane = tid & 63;
  const int l15 = lane & 15, quad = lane >> 4;
  const int id = blockIdx.x;
  const bool qk = id < 512;
  int z = 0, m0, n0;
  const float* Af = nullptr;
  const u16* Ab = nullptr;
  const u16* Bb = nullptr;
  const float* Bf = nullptr;
  if (qk) {
    z = id >> 8;
    int t = id & 255;
    m0 = (t >> 3) * 128;
    n0 = (t & 7) * 64;
    Af = z ? ks : qs;
    Bb = Wt + z * 262144;
  } else {
    int t = id - 512;
    m0 = (t >> 6) * 128;
    n0 = (t & 63) * 64;
    Ab = Wt + 2 * 262144;
    Bf = vs;
  }
  f32x4 acc[2][4];
#pragma unroll
  for (int i = 0; i < 2; i++)
#pragma unroll
    for (int j = 0; j < 4; j++) {
      f32x4 zr = {0.f, 0.f, 0.f, 0.f};
      acc[i][j] = zr;
    }
  const int srA = tid >> 1, scA = (tid & 1) * 32;
  const int srB = tid >> 2, scB = (tid & 3) * 16;
  for (int k0 = 0; k0 < 512; k0 += 64) {
    if (qk) {
      const float* ga = Af + (m0 + srA) * 512 + k0 + scA;
      u16* la = As + srA * 72 + scA;
#pragma unroll
      for (int c = 0; c < 4; ++c) {
        float4 f0 = *(const float4*)(ga + c * 8);
        float4 f1 = *(const float4*)(ga + c * 8 + 4);
        uint4 u;
        u.x = f2bf(f0.x) | ((unsigned)f2bf(f0.y) << 16);
        u.y = f2bf(f0.z) | ((unsigned)f2bf(f0.w) << 16);
        u.z = f2bf(f1.x) | ((unsigned)f2bf(f1.y) << 16);
        u.w = f2bf(f1.z) | ((unsigned)f2bf(f1.w) << 16);
        *(uint4*)(la + c * 8) = u;
      }
      const u16* gb = Bb + (n0 + srB) * 512 + k0 + scB;
      u16* lb = Bs + srB * 72 + scB;
      *(uint4*)(lb) = *(const uint4*)(gb);
      *(uint4*)(lb + 8) = *(const uint4*)(gb + 8);
    } else {
      const u16* ga = Ab + (m0 + srA) * 512 + k0 + scA;
      u16* la = As + srA * 72 + scA;
#pragma unroll
      for (int c = 0; c < 4; ++c) *(uint4*)(la + c * 8) = *(const uint4*)(ga + c * 8);
      const float* gb = Bf + (n0 + srB) * 512 + k0 + scB;
      u16* lb = Bs + srB * 72 + scB;
#pragma unroll
      for (int c = 0; c < 2; ++c) {
        float4 f0 = *(const float4*)(gb + c * 8);
        float4 f1 = *(const float4*)(gb + c * 8 + 4);
        uint4 u;
        u.x = f2bf(f0.x) | ((unsigned)f2bf(f0.y) << 16);
        u.y = f2bf(f0.z) | ((unsigned)f2bf(f0.w) << 16);
        u.z = f2bf(f1.x) | ((unsigned)f2bf(f1.y) << 16);
        u.w = f2bf(f1.z) | ((unsigned)f2bf(f1.w) << 16);
        *(uint4*)(lb + c * 8) = u;
      }
    }
    __syncthreads();
#pragma unroll
    for (int st = 0; st < 2; ++st) {
      bf16x8 af[2], bfr[4];
#pragma unroll
      for (int mt = 0; mt < 2; ++mt)
        af[mt] = *(const bf16x8*)(As + (wave * 32 + mt * 16 + l15) * 72 + st * 32 + quad * 8);
#pragma unroll
      for (int nt = 0; nt < 4; ++nt)
        bfr[nt] = *(const bf16x8*)(Bs + (nt * 16 + l15) * 72 + st * 32 + quad * 8);
#pragma unroll
      for (int mt = 0; mt < 2; ++mt)
#pragma unroll
        for (int nt = 0; nt < 4; ++nt) acc[mt][nt] = MFMA16(af[mt], bfr[nt], acc[mt][nt]);
    }
    __syncthreads();
  }
  if (qk) {
    const float* bias = z ? bk : bq;
    const float scale = z ? 1.0f : 0.125f * LOG2E;
#pragma unroll
    for (int mt = 0; mt < 2; ++mt)
#pragma unroll
      for (int nt = 0; nt < 4; ++nt)
#pragma unroll
        for (int r = 0; r < 4; ++r) {
          int row = m0 + wave * 32 + mt * 16 + quad * 4 + r;
          int col = n0 + nt * 16 + l15;
          float v = (acc[mt][nt][r] + bias[col]) * scale;
          int b = row >> 11, key = row & 2047, hh = col >> 6, dh = col & 63;
          int bhh = b * 8 + hh;
          if (z == 0) {
            qg[((bhh * 2048) + key) * 64 + dh] = f2bf(v);
          } else {
            int kt = key >> 6, tt = (key >> 5) & 1, lk = key & 31;
            int st = dh >> 4, hif = (dh >> 3) & 1, j = dh & 7;
            kg[(size_t)(bhh * 32 + kt) * 4096 + tt * 2048 + st * 512 + (hif * 32 + lk) * 8 +
               j] = f2bf(v);
          }
        }
  } else {
#pragma unroll
    for (int mt = 0; mt < 2; ++mt)
#pragma unroll
      for (int nt = 0; nt < 4; ++nt)
#pragma unroll
        for (int r = 0; r < 4; ++r) {
          int row = m0 + wave * 32 + mt * 16 + quad * 4 + r;  // dm = h*64+dh
          int col = n0 + nt * 16 + l15;                        // b*2048+key
          int hh = row >> 6, dh = row & 63, b = col >> 11, key = col & 2047;
          int bhh = b * 8 + hh;
          int kt = key >> 6, kk = key & 63, st = kk >> 4, hif = (kk >> 3) & 1, j = kk & 7;
          int h2 = dh >> 5, lk = dh & 31;
          vTg[(size_t)(bhh * 32 + kt) * 4096 + h2 * 2048 + st * 512 + (hif * 32 + lk) * 8 + j] =
              f2bf(acc[mt][nt][r] + bv[row]);
        }
  }
}

// ---------------- flash attention, 32x32 MFMA, frag-direct K/V, 4-way K-split ---------
// grid (Q/128, B*H, 4), block 256 = 4 waves x 32 q. Wave tile: 32 q x 64 keys.
// Nearest-neighbor 2048-bin f32 bias table (log2 domain, bin centers).
// V-frag loads issued BEFORE the P lgkm drain so VMEM latency overlaps softmax tail.
__global__ __launch_bounds__(256, 4) void attn_kernel(
    const u16* __restrict__ qg, const u16* __restrict__ kfrag, const u16* __restrict__ vfrag,
    const float* __restrict__ qlocs, const float* __restrict__ klocs,
    const float* __restrict__ aP, const float* __restrict__ bP, const float* __restrict__ cP,
    const int* __restrict__ vlen, u16* __restrict__ Opart, float* __restrict__ lpart) {
  constexpr int TBLN = 2048;
  constexpr float DMAX = 14.16f;  // > 10*sqrt(2) = 14.1422
  constexpr float TSCALE = (float)TBLN / DMAX;
  __shared__ u16 Ps[4][32 * 68];           // per-wave P, [q][key]  (17408 B)
  __shared__ alignas(16) float2 klb[576];  // this z-chunk's key locs (<=9 tiles), scaled
  __shared__ float tbl[TBLN];              // g(bin center)*log2e   (8192 B)
  const int tid = threadIdx.x;
  const int wave = tid >> 6, lane = tid & 63;
  const int l31 = lane & 31, hi = lane >> 5;
  const int bh = blockIdx.y, b = bh >> 3, h = bh & 7;
  const int z = blockIdx.z;
  const int vl = vlen[b];
  const int ntiles = (vl + 63) >> 6;  // in [16,32]
  const int nfull = vl >> 6;
  const int tb = ntiles >> 2, rem = ntiles & 3;  // tb >= 4: every chunk nonempty
  const int kt0 = z * tb + (z < rem ? z : rem);
  const int ktend = kt0 + tb + (z < rem ? 1 : 0);

  // per-head bias table at bin centers, log2 domain
  for (int i = tid; i < TBLN; i += 256) {
    float d = (i + 0.5f) * (DMAX / TBLN);
    float g = 0.f;
#pragma unroll
    for (int f = 0; f < 5; ++f) {
      float t = d - cP[h * 5 + f];
      g += aP[h * 5 + f] * __expf(-fabsf(bP[h * 5 + f]) * t * t);
    }
    tbl[i] = g * LOG2E;
  }
  // stage this chunk's key locations once (covers all tiles incl. the partial one)
  const int nk = (ktend - kt0) * 64;
  for (int i = tid; i < nk; i += 256) {
    float2 kl = *(const float2*)(klocs + (b * 2048 + kt0 * 64 + i) * 2);
    klb[i] = make_float2(kl.x * TSCALE, kl.y * TSCALE);
  }
  __syncthreads();  // tbl + klb visible; the ONLY block barrier

  const int qrow = blockIdx.x * 128 + wave * 32 + l31;
  bf16x8 aq[4];  // Q B-operand: B[k=dh][n=q], k = st*16 + hi*8 + j
  {
    const u16* qr = qg + (bh * 2048 + qrow) * 64 + hi * 8;
#pragma unroll
    for (int st = 0; st < 4; ++st) aq[st] = *(const bf16x8*)(qr + st * 16);
  }
  float qpx, qpy;
  {
    float2 p = *(const float2*)(qlocs + (b * 2048 + qrow) * 2);
    qpx = p.x * TSCALE;
    qpy = p.y * TSCALE;
  }
  float l_ = 0.f;
  f32x16 oacc[2];
#pragma unroll
  for (int i = 0; i < 2; ++i)
#pragma unroll
    for (int j = 0; j < 16; ++j) oacc[i][j] = 0.f;
  u16* pw = Ps[wave];

  auto tile = [&](int kt, auto mc) {
    constexpr bool MASKED = decltype(mc)::value;
    const int k0 = kt * 64;
    const int rt64 = (kt - kt0) * 64;
    const u16* fb = kfrag + (size_t)(bh * 32 + kt) * 4096 + lane * 8;
    const u16* vb = vfrag + (size_t)(bh * 32 + kt) * 4096 + lane * 8;
#pragma unroll
    for (int t = 0; t < 2; ++t) {
      bf16x8 kf[4];
#pragma unroll
      for (int st = 0; st < 4; ++st)
        kf[st] = *(const bf16x8*)(fb + t * 2048 + st * 512);  // coalesced 1KB global
      // S^T = K*Q^T: D[key = t*32 + (reg&3)+8*(reg>>2)+4*hi][q = l31]
      f32x16 s;
#pragma unroll
      for (int j = 0; j < 16; ++j) s[j] = 0.f;
#pragma unroll
      for (int st = 0; st < 4; ++st) s = MFMA32(kf[st], aq[st], s);
      // bias (nearest-bin lookup) + exp2 + P write, per 4-key group
#pragma unroll
      for (int g = 0; g < 4; ++g) {
        const int kl0 = t * 32 + hi * 4 + g * 8;
        float4 ka = *(const float4*)(&klb[rt64 + kl0]);      // keys kl0, kl0+1
        float4 kb = *(const float4*)(&klb[rt64 + kl0 + 2]);  // keys kl0+2, kl0+3
        float kx[4] = {ka.x, ka.z, kb.x, kb.z};
        float ky[4] = {ka.y, ka.w, kb.y, kb.w};
        float p[4];
#pragma unroll
        for (int j = 0; j < 4; ++j) {
          float dx = qpx - kx[j], dy = qpy - ky[j];
          float t_ = __builtin_amdgcn_sqrtf(fmaf(dx, dx, dy * dy));  // = d * TSCALE
          int ti = (int)t_;  // <= 2045 by construction
          float v = s[g * 4 + j] + tbl[ti];
          if (MASKED) v = (k0 + kl0 + j < vl) ? v : -1e30f;
          p[j] = __builtin_amdgcn_exp2f(v);
          l_ += p[j];
        }
        uint2 w;
        w.x = f2bf_fast(p[0]) | ((unsigned)f2bf_fast(p[1]) << 16);
        w.y = f2bf_fast(p[2]) | ((unsigned)f2bf_fast(p[3]) << 16);
        *(uint2*)(pw + l31 * 68 + kl0) = w;
      }
    }
    // issue V-frag loads BEFORE the LDS drain: VMEM latency overlaps lgkm wait + pf reads
    bf16x8 vf[2][4];
#pragma unroll
    for (int h2 = 0; h2 < 2; ++h2)
#pragma unroll
      for (int st = 0; st < 4; ++st)
        vf[h2][st] = *(const bf16x8*)(vb + h2 * 2048 + st * 512);  // coalesced 1KB global
    // P tile wave-private: drain LDS writes, no barrier
    __asm__ volatile("s_waitcnt lgkmcnt(0)" ::: "memory");
    // O^T += V^T * P: D[dh][q = l31]
#pragma unroll
    for (int st = 0; st < 4; ++st) {
      bf16x8 pf = *(const bf16x8*)(pw + l31 * 68 + st * 16 + hi * 8);
#pragma unroll
      for (int h2 = 0; h2 < 2; ++h2) oacc[h2] = MFMA32(vf[h2][st], pf, oacc[h2]);
    }
  };

  const int fullend = ktend < nfull ? ktend : nfull;
  for (int kt = kt0; kt < fullend; ++kt) tile(kt, FalseT{});
  if (ktend > nfull) tile(nfull, TrueT{});

  l_ += __shfl_xor(l_, 32);
  if (hi == 0) lpart[z * 32768 + bh * 2048 + qrow] = l_;
  u16* ob = Opart + ((size_t)(z * 16 + bh) * 2048 + qrow) * 64;
#pragma unroll
  for (int h2 = 0; h2 < 2; ++h2)
#pragma unroll
    for (int g = 0; g < 4; ++g) {
      const int dh0 = h2 * 32 + hi * 4 + g * 8;
      uint2 w;
      w.x = f2bf(oacc[h2][g * 4 + 0]) | ((unsigned)f2bf(oacc[h2][g * 4 + 1]) << 16);
      w.y = f2bf(oacc[h2][g * 4 + 2]) | ((unsigned)f2bf(oacc[h2][g * 4 + 3]) << 16);
      *(uint2*)(ob + dh0) = w;
    }
}

// ---------------- O-projection GEMM with fused 4-partial combine ----------------------
// tile 64x64, grid (64,8) = 512 blocks (2/CU, 16 waves/CU). A-stage sums the 4 z-partials
// (contiguous 64-elem rows per z, fully coalesced), normalizes by sum(lpart), packs bf16.
__global__ __launch_bounds__(256) void out_gemm(const u16* __restrict__ Opart,
                                                const float* __restrict__ lpart,
                                                const u16* __restrict__ Wt,
                                                const float* __restrict__ bo,
                                                float* __restrict__ out) {
  __shared__ u16 As[64 * 72];
  __shared__ u16 Bs[64 * 72];
  const u16* WoT = Wt + 3 * 262144;
  const int tid = threadIdx.x;
  const int wave = tid >> 6, lane = tid & 63;
  const int l15 = lane & 15, quad = lane >> 4;
  const int m0 = blockIdx.x * 64, n0 = blockIdx.y * 64;
  f32x4 acc[4];
#pragma unroll
  for (int j = 0; j < 4; j++) {
    f32x4 zr = {0.f, 0.f, 0.f, 0.f};
    acc[j] = zr;
  }
  const int sr = tid >> 2, sc = (tid & 3) * 16;
  const int row = m0 + sr, b = row >> 11, qq = row & 2047;
  for (int k0 = 0; k0 < 512; k0 += 64) {
    const int h = k0 >> 6;
    const int base = (b * 8 + h) * 2048 + qq;  // row into [z][32768] partial space
    float l = lpart[base] + lpart[32768 + base] + lpart[2 * 32768 + base] +
              lpart[3 * 32768 + base];
    const float inv = 1.f / l;
    float vals[16];
#pragma unroll
    for (int e = 0; e < 16; ++e) vals[e] = 0.f;
#pragma unroll
    for (int zz = 0; zz < 4; ++zz) {
      const u16* op = Opart + ((size_t)(zz * 32768) + base) * 64 + sc;
#pragma unroll
      for (int c = 0; c < 2; ++c) {
        bf16x8 o8 = *(const bf16x8*)(op + c * 8);
#pragma unroll
        for (int j = 0; j < 8; ++j) vals[c * 8 + j] += (float)o8[j];
      }
    }
    u16* la = As + sr * 72 + sc;
#pragma unroll
    for (int c = 0; c < 2; ++c) {
      uint4 u;
      u.x = f2bf(vals[c * 8 + 0] * inv) | ((unsigned)f2bf(vals[c * 8 + 1] * inv) << 16);
      u.y = f2bf(vals[c * 8 + 2] * inv) | ((unsigned)f2bf(vals[c * 8 + 3] * inv) << 16);
      u.z = f2bf(vals[c * 8 + 4] * inv) | ((unsigned)f2bf(vals[c * 8 + 5] * inv) << 16);
      u.w = f2bf(vals[c * 8 + 6] * inv) | ((unsigned)f2bf(vals[c * 8 + 7] * inv) << 16);
      *(uint4*)(la + c * 8) = u;
    }
    const u16* gb = WoT + (n0 + sr) * 512 + k0 + sc;
    u16* lb = Bs + sr * 72 + sc;
    *(uint4*)(lb) = *(const uint4*)(gb);
    *(uint4*)(lb + 8) = *(const uint4*)(gb + 8);
    __syncthreads();
#pragma unroll
    for (int st = 0; st < 2; ++st) {
      bf16x8 af = *(const bf16x8*)(As + (wave * 16 + l15) * 72 + st * 32 + quad * 8);
#pragma unroll
      for (int nt = 0; nt < 4; ++nt) {
        bf16x8 bfr = *(const bf16x8*)(Bs + (nt * 16 + l15) * 72 + st * 32 + quad * 8);
        acc[nt] = MFMA16(af, bfr, acc[nt]);
      }
    }
    __syncthreads();
  }
#pragma unroll
  for (int nt = 0; nt < 4; ++nt)
#pragma unroll
    for (int r = 0; r < 4; ++r) {
      int rrow = m0 + wave * 16 + quad * 4 + r;
      int col = n0 + nt * 16 + l15;
      out[rrow * 512 + col] = acc[nt][r] + bo[col];
    }
}

extern "C" void kernel_launch(void* const* d_in, const int* in_sizes, int n_in, void* d_out,
                              int out_size, void* d_ws, size_t ws_size, hipStream_t stream) {
  const float* qs = (const float*)d_in[0];
  const float* ks = (const float*)d_in[1];
  const float* vs = (const float*)d_in[2];
  const float* qlocs = (const float*)d_in[3];
  const float* klocs = (const float*)d_in[4];
  const float* Wq = (const float*)d_in[5];
  const float* bq = (const float*)d_in[6];
  const float* Wk = (const float*)d_in[7];
  const float* bk = (const float*)d_in[8];
  const float* Wv = (const float*)d_in[9];
  const float* bv = (const float*)d_in[10];
  const float* Wo = (const float*)d_in[11];
  const float* bo = (const float*)d_in[12];
  const float* aP = (const float*)d_in[13];
  const float* bP = (const float*)d_in[14];
  const float* cP = (const float*)d_in[15];
  const int* vlen = (const int*)d_in[16];
  float* out = (float*)d_out;

  u16* Wt = (u16*)d_ws;        // 4 x [512,512] bf16 W^T (2 MB)
  u16* qg = Wt + 4 * 262144;   // [B,H,Q,DH] bf16 row-major (4 MB)
  u16* kg = qg + 2097152;      // K-frag layout [bh][kt][t][st][lane][8] (4 MB)
  u16* vTg = kg + 2097152;     // V-frag layout [bh][kt][h2][st][lane][8] (4 MB)
  u16* Opart = vTg + 2097152;  // [4][16][2048][64] bf16 (16 MB)
  float* lpart = (float*)(Opart + (size_t)4 * 2097152);  // [4][32768]

  transpose_w_kernel<<<dim3(16, 16, 4), dim3(32, 8), 0, stream>>>(Wq, Wk, Wv, Wo, Wt);
  qkv_gemm<<<768, 256, 0, stream>>>(qs, ks, vs, Wt, bq, bk, bv, qg, kg, vTg);
  attn_kernel<<<dim3(16, 16, 4), 256, 0, stream>>>(qg, kg, vTg, qlocs, klocs, aP, bP, cP, vlen,
                                                   Opart, lpart);
  out_gemm<<<dim3(64, 8), 256, 0, stream>>>(Opart, lpart, Wt, bo, out);
}